// Round 9
// baseline (254.459 us; speedup 1.0000x reference)
//
#include <hip/hip_runtime.h>
#include <stdint.h>

#define B 4096
#define D 2048
#define BK 128          // k-slab per barrier (fp8 elements; 128 B rows)

typedef unsigned long long ull;
typedef float f32x4 __attribute__((ext_vector_type(4)));
typedef int i32x4 __attribute__((ext_vector_type(4)));
typedef int i32x8 __attribute__((ext_vector_type(8)));

#define SENT_P 0x00000000FFFFFFFFull  // dist=0.0, ~idx -> "no positive seen"
#define SENT_N (~0ull)                // +inf      -> "no negative seen"

// ---------------- async global->LDS (16B per lane, wave-uniform LDS base) ----
__device__ __forceinline__ void async_copy16(const unsigned char* g, unsigned char* l) {
  __builtin_amdgcn_global_load_lds(
      (const __attribute__((address_space(1))) unsigned int*)g,
      (__attribute__((address_space(3))) unsigned int*)l,
      16, 0, 0);
}

// ---------------- fp32 -> fp8 e4m3 (OCP) + norms + sentinel init ------------
__global__ void k_convert_sq(const float* __restrict__ emb,
                             unsigned char* __restrict__ embq,
                             float* __restrict__ sq,
                             float* __restrict__ rs,
                             ull* __restrict__ bp,
                             ull* __restrict__ bn) {
  const int row = blockIdx.x, t = threadIdx.x;
  const float4* src = (const float4*)(emb + (size_t)row * D);
  float4 v0 = src[2 * t], v1 = src[2 * t + 1];
  float s = v0.x * v0.x + v0.y * v0.y + v0.z * v0.z + v0.w * v0.w
          + v1.x * v1.x + v1.y * v1.y + v1.z * v1.z + v1.w * v1.w;
  float sm = v0.x + v0.y + v0.z + v0.w + v1.x + v1.y + v1.z + v1.w;

  // pack 8 floats -> 8 fp8 bytes (v_cvt_pk_fp8_f32, OCP e4m3fn on gfx950)
  unsigned w0 = __builtin_amdgcn_cvt_pk_fp8_f32(v0.x, v0.y, 0, false);
  w0 = __builtin_amdgcn_cvt_pk_fp8_f32(v0.z, v0.w, w0, true);
  unsigned w1 = __builtin_amdgcn_cvt_pk_fp8_f32(v1.x, v1.y, 0, false);
  w1 = __builtin_amdgcn_cvt_pk_fp8_f32(v1.z, v1.w, w1, true);
  uint2 o; o.x = w0; o.y = w1;
  ((uint2*)(embq + (size_t)row * D))[t] = o;

  for (int off = 32; off; off >>= 1) {
    s  += __shfl_down(s, off, 64);
    sm += __shfl_down(sm, off, 64);
  }
  __shared__ float ps[4], pm[4];
  int lane = t & 63, wave = t >> 6;
  if (lane == 0) { ps[wave] = s; pm[wave] = sm; }
  __syncthreads();
  if (t == 0) {
    sq[row] = ps[0] + ps[1] + ps[2] + ps[3];
    rs[row] = pm[0] + pm[1] + pm[2] + pm[3];
    bp[row] = SENT_P;
    bn[row] = SENT_N;
  }
}

// ---------------- fused symmetric fp8 GEMM + hard pos/neg selection ---------
// 64x128 tiles covering the strict upper triangle (j > i): 1056 blocks,
// sequential triangular decode (best measured mapping). BK=128 fp8 = 128 B
// rows -> 16 k-iterations. Engine: mfma_scale_f32_16x16x128_f8f6f4 with
// both scales = e8m0 127 (x1.0, exact identity) -> plain fp8 GEMM at the MX
// rate. Its A/B fragment (32 B/lane, k = q*32..+32, CONTIGUOUS) matches the
// global-contiguous 16 B staging chunks, so fragment reads are ds_read_b128
// at the uniform 8-lanes/slot pattern that measured 0 bank conflicts (R4),
// eliminating R8's 6.5M b64 even-bank conflicts. 8 MFMA/wave per k-iter.
// Rows are 8 chunks of 16 B; chunk c stored at slot c ^ (row&7) keeps
// global_load_lds's wave-uniform-base layout.
__launch_bounds__(256, 4)
__global__ void k_gemm_select(const unsigned char* __restrict__ embq,
                              const float* __restrict__ sq,
                              const int* __restrict__ labels,
                              ull* __restrict__ best_pos,
                              ull* __restrict__ best_neg) {
  __shared__ unsigned char ldsA[64 * BK];    // 8 KB
  __shared__ unsigned char ldsB[128 * BK];   // 16 KB

  // linear bid -> (by in [0,64), bx in [0,32)) with bx*128+127 > by*64
  int rem = blockIdx.x, p = 0;
  while (rem >= 2 * (32 - p)) { rem -= 2 * (32 - p); ++p; }
  int by = 2 * p;
  int c = 32 - p;
  if (rem >= c) { by += 1; rem -= c; }
  const int bx = p + rem;

  const int tid  = threadIdx.x;
  const int lane = tid & 63;
  const int wave = tid >> 6;
  const int wm = wave >> 1, wn = wave & 1;
  const int q = lane >> 4, m15 = lane & 15;
  const int ibase = by * 64, jbase = bx * 128;

  // fragment read offsets (bytes): lane (q,m15) needs k-bytes [q*32, q*32+32)
  // of its row = chunks 2q, 2q+1 -> slots (2q+h) ^ (row&7), h in {0,1}.
  int aoff[2][2], boff[4][2];
#pragma unroll
  for (int xg = 0; xg < 2; ++xg) {
    int row = wm * 32 + xg * 16 + m15;
#pragma unroll
    for (int h = 0; h < 2; ++h)
      aoff[xg][h] = row * BK + (((2 * q + h) ^ (row & 7)) * 16);
  }
#pragma unroll
  for (int xg = 0; xg < 4; ++xg) {
    int row = wn * 64 + xg * 16 + m15;
#pragma unroll
    for (int h = 0; h < 2; ++h)
      boff[xg][h] = row * BK + (((2 * q + h) ^ (row & 7)) * 16);
  }

  const int srow = lane >> 3;  // row within 8-row staging group
  const int slot = lane & 7;   // 16B slot within 128B row

  // staging base pointers (6 wave-uniform issues per slab)
  const unsigned char* gA[2];
  const unsigned char* gB[4];
  int lA[2], lB[4];
#pragma unroll
  for (int pp = 0; pp < 2; ++pp) {
    int r0  = wave * 16 + pp * 8;  // wave-uniform
    int row = r0 + srow;
    int g   = (slot ^ (row & 7)) * 16;
    gA[pp] = embq + (size_t)(ibase + row) * D + g;
    lA[pp] = r0 * BK;
  }
#pragma unroll
  for (int pp = 0; pp < 4; ++pp) {
    int r0  = wave * 32 + pp * 8;  // wave-uniform
    int row = r0 + srow;
    int g   = (slot ^ (row & 7)) * 16;
    gB[pp] = embq + (size_t)(jbase + row) * D + g;
    lB[pp] = r0 * BK;
  }

  f32x4 acc[2][4];
  const f32x4 z = {0.f, 0.f, 0.f, 0.f};
#pragma unroll
  for (int a = 0; a < 2; ++a)
#pragma unroll
    for (int b = 0; b < 4; ++b) acc[a][b] = z;

  for (int kb = 0; kb < D; kb += BK) {
    __syncthreads();
#pragma unroll
    for (int pp = 0; pp < 2; ++pp) async_copy16(gA[pp] + kb, &ldsA[lA[pp]]);
#pragma unroll
    for (int pp = 0; pp < 4; ++pp) async_copy16(gB[pp] + kb, &ldsB[lB[pp]]);
    __syncthreads();

    i32x8 af[2], bfr[4];
#pragma unroll
    for (int xg = 0; xg < 2; ++xg) {
      i32x4 lo = *(const i32x4*)&ldsA[aoff[xg][0]];
      i32x4 hi = *(const i32x4*)&ldsA[aoff[xg][1]];
      af[xg] = __builtin_shufflevector(lo, hi, 0, 1, 2, 3, 4, 5, 6, 7);
    }
#pragma unroll
    for (int xg = 0; xg < 4; ++xg) {
      i32x4 lo = *(const i32x4*)&ldsB[boff[xg][0]];
      i32x4 hi = *(const i32x4*)&ldsB[boff[xg][1]];
      bfr[xg] = __builtin_shufflevector(lo, hi, 0, 1, 2, 3, 4, 5, 6, 7);
    }
#pragma unroll
    for (int mi = 0; mi < 2; ++mi)
#pragma unroll
      for (int ni = 0; ni < 4; ++ni)
        acc[mi][ni] = __builtin_amdgcn_mfma_scale_f32_16x16x128_f8f6f4(
            af[mi], bfr[ni], acc[mi][ni],
            0 /*cbsz: fp8 e4m3*/, 0 /*blgp: fp8 e4m3*/,
            0, 127 /*scaleA = 2^0*/, 0, 127 /*scaleB = 2^0*/);
  }

  // ---- epilogue (C/D layout shape-determined: col=lane&15, row=q*4+r) ----
  float sqj[4];
  int labj[4];
#pragma unroll
  for (int ni = 0; ni < 4; ++ni) {
    int jj = jbase + wn * 64 + ni * 16 + m15;
    sqj[ni] = sq[jj];
    labj[ni] = labels[jj];
  }

  ull colBp[4], colBn[4];
#pragma unroll
  for (int ni = 0; ni < 4; ++ni) { colBp[ni] = SENT_P; colBn[ni] = SENT_N; }

#pragma unroll
  for (int mi = 0; mi < 2; ++mi) {
#pragma unroll
    for (int r = 0; r < 4; ++r) {
      const int i = ibase + wm * 32 + mi * 16 + q * 4 + r;
      const float si = sq[i];
      const int li = labels[i];
      ull bp = SENT_P;
      ull bn = SENT_N;
#pragma unroll
      for (int ni = 0; ni < 4; ++ni) {
        int jj = jbase + wn * 64 + ni * 16 + m15;
        if (jj > i) {  // strict upper triangle only
          float dot = acc[mi][ni][r];
          float d2 = si + sqj[ni] - 2.0f * dot;
          float dist = sqrtf(fmaxf(d2, 0.0f));
          ull pv = ((ull)__float_as_uint(dist)) << 32;
          if (labj[ni] == li) {
            ull cr = pv | (unsigned)(~jj);  // max -> smallest idx wins ties
            bp = bp > cr ? bp : cr;
            ull cc = pv | (unsigned)(~i);
            colBp[ni] = colBp[ni] > cc ? colBp[ni] : cc;
          } else {
            ull cr = pv | (unsigned)jj;     // min -> smallest idx wins ties
            bn = bn < cr ? bn : cr;
            ull cc = pv | (unsigned)i;
            colBn[ni] = colBn[ni] < cc ? colBn[ni] : cc;
          }
        }
      }
      // row-i reduction across the 16 column lanes (m15 bits)
#pragma unroll
      for (int off = 1; off <= 8; off <<= 1) {
        ull op = __shfl_xor(bp, off, 64);
        ull on = __shfl_xor(bn, off, 64);
        bp = bp > op ? bp : op;
        bn = bn < on ? bn : on;
      }
      if (m15 == 0) {
        if (bp != SENT_P) atomicMax(&best_pos[i], bp);
        if (bn != SENT_N) atomicMin(&best_neg[i], bn);
      }
    }
  }

  // col-j reduction across the 4 q lane-groups
#pragma unroll
  for (int ni = 0; ni < 4; ++ni) {
    ull cp = colBp[ni], cn = colBn[ni];
#pragma unroll
    for (int off = 16; off <= 32; off <<= 1) {
      ull op = __shfl_xor(cp, off, 64);
      ull on = __shfl_xor(cn, off, 64);
      cp = cp > op ? cp : op;
      cn = cn < on ? cn : on;
    }
    if (q == 0) {
      int j = jbase + wn * 64 + ni * 16 + m15;
      if (cp != SENT_P) atomicMax(&best_pos[j], cp);
      if (cn != SENT_N) atomicMin(&best_neg[j], cn);
    }
  }
}

// ---------------- loss + finalize in one single-block kernel ----------------
// valid anchor <=> bp != SENT_P && bn != SENT_N. dp/dn from the packed fp32
// dist plus the eps correction:
//   ||x+eps*1||^2 = ||x||^2 + 2 eps (sum_i - sum_j) + D eps^2
__global__ void k_loss_final(const ull* __restrict__ best_pos,
                             const ull* __restrict__ best_neg,
                             const float* __restrict__ rs,
                             float* __restrict__ out) {
  float per = 0.0f;
  int v = 0;
  for (int i = threadIdx.x; i < B; i += 1024) {
    ull bp = best_pos[i], bn = best_neg[i];
    if (bp != SENT_P && bn != SENT_N) {
      unsigned pRaw = ~(unsigned)bp;
      unsigned nRaw = (unsigned)bn;
      int pi = pRaw < (unsigned)B ? (int)pRaw : 0;
      int ni = nRaw < (unsigned)B ? (int)nRaw : 0;
      float distp = __uint_as_float((unsigned)(bp >> 32));
      float distn = __uint_as_float((unsigned)(bn >> 32));
      float ri = rs[i];
      const float e = 1e-6f, de2 = (float)D * 1e-12f;
      float dp2 = distp * distp + 2.0f * e * (ri - rs[pi]) + de2;
      float dn2 = distn * distn + 2.0f * e * (ri - rs[ni]) + de2;
      float dp = sqrtf(fmaxf(dp2, 0.0f));
      float dn = sqrtf(fmaxf(dn2, 0.0f));
      per += fmaxf(dp - dn + 0.3f, 0.0f);
      v += 1;
    }
  }
  for (int off = 32; off; off >>= 1) {
    per += __shfl_down(per, off, 64);
    v   += __shfl_down(v, off, 64);
  }
  __shared__ float pps[16];
  __shared__ int pvs[16];
  int lane = threadIdx.x & 63, wave = threadIdx.x >> 6;
  if (lane == 0) { pps[wave] = per; pvs[wave] = v; }
  __syncthreads();
  if (threadIdx.x == 0) {
    float t = 0.f;
    int cv = 0;
#pragma unroll
    for (int w = 0; w < 16; ++w) { t += pps[w]; cv += pvs[w]; }
    out[0] = cv > 0 ? t / (float)cv : 0.0f;
  }
}

// ---------------- launch -----------------------------------------------------
extern "C" void kernel_launch(void* const* d_in, const int* in_sizes, int n_in,
                              void* d_out, int out_size, void* d_ws, size_t ws_size,
                              hipStream_t stream) {
  const float* emb = (const float*)d_in[0];
  const int* labels = (const int*)d_in[1];
  float* out = (float*)d_out;
  char* ws = (char*)d_ws;

  const size_t off_embq = 0;
  const size_t off_sq   = off_embq + (size_t)B * D;       // 8 MiB
  const size_t off_rs   = off_sq + (size_t)B * 4;
  const size_t off_bp   = off_rs + (size_t)B * 4;
  const size_t off_bn   = off_bp + (size_t)B * 8;

  unsigned char* embq = (unsigned char*)(ws + off_embq);
  float* sq   = (float*)(ws + off_sq);
  float* rs   = (float*)(ws + off_rs);
  ull* bp     = (ull*)(ws + off_bp);
  ull* bn     = (ull*)(ws + off_bn);

  hipLaunchKernelGGL(k_convert_sq, dim3(B), dim3(256), 0, stream,
                     emb, embq, sq, rs, bp, bn);
  hipLaunchKernelGGL(k_gemm_select, dim3(1056), dim3(256), 0, stream,
                     embq, sq, labels, bp, bn);
  hipLaunchKernelGGL(k_loss_final, dim3(1), dim3(1024), 0, stream,
                     bp, bn, rs, out);
}

// Round 10
// 200.445 us; speedup vs baseline: 1.2695x; 1.2695x over previous
//
#include <hip/hip_runtime.h>
#include <stdint.h>

#define B 4096
#define D 2048
#define BK 128          // k-slab per barrier (fp8 elements; 128 B rows)

typedef unsigned long long ull;
typedef float f32x4 __attribute__((ext_vector_type(4)));
typedef int i32x4 __attribute__((ext_vector_type(4)));
typedef int i32x8 __attribute__((ext_vector_type(8)));

#define SENT_P 0x00000000FFFFFFFFull  // dist=0.0, ~idx -> "no positive seen"
#define SENT_N (~0ull)                // +inf      -> "no negative seen"

// ---------------- async global->LDS (16B per lane, wave-uniform LDS base) ----
__device__ __forceinline__ void async_copy16(const unsigned char* g, unsigned char* l) {
  __builtin_amdgcn_global_load_lds(
      (const __attribute__((address_space(1))) unsigned int*)g,
      (__attribute__((address_space(3))) unsigned int*)l,
      16, 0, 0);
}

// ---------------- fp32 -> fp8 e4m3 (OCP) + norms + sentinel init ------------
__global__ void k_convert_sq(const float* __restrict__ emb,
                             unsigned char* __restrict__ embq,
                             float* __restrict__ sq,
                             float* __restrict__ rs,
                             ull* __restrict__ bp,
                             ull* __restrict__ bn) {
  const int row = blockIdx.x, t = threadIdx.x;
  const float4* src = (const float4*)(emb + (size_t)row * D);
  float4 v0 = src[2 * t], v1 = src[2 * t + 1];
  float s = v0.x * v0.x + v0.y * v0.y + v0.z * v0.z + v0.w * v0.w
          + v1.x * v1.x + v1.y * v1.y + v1.z * v1.z + v1.w * v1.w;
  float sm = v0.x + v0.y + v0.z + v0.w + v1.x + v1.y + v1.z + v1.w;

  // pack 8 floats -> 8 fp8 bytes (v_cvt_pk_fp8_f32, OCP e4m3fn on gfx950)
  unsigned w0 = __builtin_amdgcn_cvt_pk_fp8_f32(v0.x, v0.y, 0, false);
  w0 = __builtin_amdgcn_cvt_pk_fp8_f32(v0.z, v0.w, w0, true);
  unsigned w1 = __builtin_amdgcn_cvt_pk_fp8_f32(v1.x, v1.y, 0, false);
  w1 = __builtin_amdgcn_cvt_pk_fp8_f32(v1.z, v1.w, w1, true);
  uint2 o; o.x = w0; o.y = w1;
  ((uint2*)(embq + (size_t)row * D))[t] = o;

  for (int off = 32; off; off >>= 1) {
    s  += __shfl_down(s, off, 64);
    sm += __shfl_down(sm, off, 64);
  }
  __shared__ float ps[4], pm[4];
  int lane = t & 63, wave = t >> 6;
  if (lane == 0) { ps[wave] = s; pm[wave] = sm; }
  __syncthreads();
  if (t == 0) {
    sq[row] = ps[0] + ps[1] + ps[2] + ps[3];
    rs[row] = pm[0] + pm[1] + pm[2] + pm[3];
    bp[row] = SENT_P;
    bn[row] = SENT_N;
  }
}

// ---------------- fused symmetric fp8 GEMM + hard pos/neg selection ---------
// 64x128 tiles covering the strict upper triangle (j > i): 1056 blocks,
// sequential triangular decode (best measured mapping). BK=128 fp8 = 128 B
// rows -> 16 k-iterations. Engine: mfma_scale_f32_16x16x128_f8f6f4, scales
// = e8m0 127 (x1.0 identity) -> plain fp8 GEMM at the MX rate, verified
// bit-correct in R9. R9's regression was VGPR starvation (launch_bounds
// (256,4) capped at 64 VGPRs -> 265 MB/dispatch scratch spill traffic);
// the ~110-reg working set (48 frag + 32 acc + addr) needs the (256,3)
// cap (~170). Fragment reads: 12 ds_read_b128 per wave-iter at the
// full-slot-spread swizzle (slot = chunk ^ (row&7)).
__launch_bounds__(256, 3)
__global__ void k_gemm_select(const unsigned char* __restrict__ embq,
                              const float* __restrict__ sq,
                              const int* __restrict__ labels,
                              ull* __restrict__ best_pos,
                              ull* __restrict__ best_neg) {
  __shared__ unsigned char ldsA[64 * BK];    // 8 KB
  __shared__ unsigned char ldsB[128 * BK];   // 16 KB

  // linear bid -> (by in [0,64), bx in [0,32)) with bx*128+127 > by*64
  int rem = blockIdx.x, p = 0;
  while (rem >= 2 * (32 - p)) { rem -= 2 * (32 - p); ++p; }
  int by = 2 * p;
  int c = 32 - p;
  if (rem >= c) { by += 1; rem -= c; }
  const int bx = p + rem;

  const int tid  = threadIdx.x;
  const int lane = tid & 63;
  const int wave = tid >> 6;
  const int wm = wave >> 1, wn = wave & 1;
  const int q = lane >> 4, m15 = lane & 15;
  const int ibase = by * 64, jbase = bx * 128;

  // fragment read offsets (bytes): lane (q,m15) needs k-bytes [q*32, q*32+32)
  // of its row = chunks 2q, 2q+1 -> slots (2q+h) ^ (row&7), h in {0,1}.
  int aoff[2][2], boff[4][2];
#pragma unroll
  for (int xg = 0; xg < 2; ++xg) {
    int row = wm * 32 + xg * 16 + m15;
#pragma unroll
    for (int h = 0; h < 2; ++h)
      aoff[xg][h] = row * BK + (((2 * q + h) ^ (row & 7)) * 16);
  }
#pragma unroll
  for (int xg = 0; xg < 4; ++xg) {
    int row = wn * 64 + xg * 16 + m15;
#pragma unroll
    for (int h = 0; h < 2; ++h)
      boff[xg][h] = row * BK + (((2 * q + h) ^ (row & 7)) * 16);
  }

  const int srow = lane >> 3;  // row within 8-row staging group
  const int slot = lane & 7;   // 16B slot within 128B row

  // staging base pointers (6 wave-uniform issues per slab)
  const unsigned char* gA[2];
  const unsigned char* gB[4];
  int lA[2], lB[4];
#pragma unroll
  for (int pp = 0; pp < 2; ++pp) {
    int r0  = wave * 16 + pp * 8;  // wave-uniform
    int row = r0 + srow;
    int g   = (slot ^ (row & 7)) * 16;
    gA[pp] = embq + (size_t)(ibase + row) * D + g;
    lA[pp] = r0 * BK;
  }
#pragma unroll
  for (int pp = 0; pp < 4; ++pp) {
    int r0  = wave * 32 + pp * 8;  // wave-uniform
    int row = r0 + srow;
    int g   = (slot ^ (row & 7)) * 16;
    gB[pp] = embq + (size_t)(jbase + row) * D + g;
    lB[pp] = r0 * BK;
  }

  f32x4 acc[2][4];
  const f32x4 z = {0.f, 0.f, 0.f, 0.f};
#pragma unroll
  for (int a = 0; a < 2; ++a)
#pragma unroll
    for (int b = 0; b < 4; ++b) acc[a][b] = z;

  for (int kb = 0; kb < D; kb += BK) {
    __syncthreads();
#pragma unroll
    for (int pp = 0; pp < 2; ++pp) async_copy16(gA[pp] + kb, &ldsA[lA[pp]]);
#pragma unroll
    for (int pp = 0; pp < 4; ++pp) async_copy16(gB[pp] + kb, &ldsB[lB[pp]]);
    __syncthreads();

    i32x8 af[2], bfr[4];
#pragma unroll
    for (int xg = 0; xg < 2; ++xg) {
      i32x4 lo = *(const i32x4*)&ldsA[aoff[xg][0]];
      i32x4 hi = *(const i32x4*)&ldsA[aoff[xg][1]];
      af[xg] = __builtin_shufflevector(lo, hi, 0, 1, 2, 3, 4, 5, 6, 7);
    }
#pragma unroll
    for (int xg = 0; xg < 4; ++xg) {
      i32x4 lo = *(const i32x4*)&ldsB[boff[xg][0]];
      i32x4 hi = *(const i32x4*)&ldsB[boff[xg][1]];
      bfr[xg] = __builtin_shufflevector(lo, hi, 0, 1, 2, 3, 4, 5, 6, 7);
    }
#pragma unroll
    for (int mi = 0; mi < 2; ++mi)
#pragma unroll
      for (int ni = 0; ni < 4; ++ni)
        acc[mi][ni] = __builtin_amdgcn_mfma_scale_f32_16x16x128_f8f6f4(
            af[mi], bfr[ni], acc[mi][ni],
            0 /*cbsz: fp8 e4m3*/, 0 /*blgp: fp8 e4m3*/,
            0, 127 /*scaleA = 2^0*/, 0, 127 /*scaleB = 2^0*/);
  }

  // ---- epilogue (C/D layout shape-determined: col=lane&15, row=q*4+r) ----
  float sqj[4];
  int labj[4];
#pragma unroll
  for (int ni = 0; ni < 4; ++ni) {
    int jj = jbase + wn * 64 + ni * 16 + m15;
    sqj[ni] = sq[jj];
    labj[ni] = labels[jj];
  }

  ull colBp[4], colBn[4];
#pragma unroll
  for (int ni = 0; ni < 4; ++ni) { colBp[ni] = SENT_P; colBn[ni] = SENT_N; }

#pragma unroll
  for (int mi = 0; mi < 2; ++mi) {
#pragma unroll
    for (int r = 0; r < 4; ++r) {
      const int i = ibase + wm * 32 + mi * 16 + q * 4 + r;
      const float si = sq[i];
      const int li = labels[i];
      ull bp = SENT_P;
      ull bn = SENT_N;
#pragma unroll
      for (int ni = 0; ni < 4; ++ni) {
        int jj = jbase + wn * 64 + ni * 16 + m15;
        if (jj > i) {  // strict upper triangle only
          float dot = acc[mi][ni][r];
          float d2 = si + sqj[ni] - 2.0f * dot;
          float dist = sqrtf(fmaxf(d2, 0.0f));
          ull pv = ((ull)__float_as_uint(dist)) << 32;
          if (labj[ni] == li) {
            ull cr = pv | (unsigned)(~jj);  // max -> smallest idx wins ties
            bp = bp > cr ? bp : cr;
            ull cc = pv | (unsigned)(~i);
            colBp[ni] = colBp[ni] > cc ? colBp[ni] : cc;
          } else {
            ull cr = pv | (unsigned)jj;     // min -> smallest idx wins ties
            bn = bn < cr ? bn : cr;
            ull cc = pv | (unsigned)i;
            colBn[ni] = colBn[ni] < cc ? colBn[ni] : cc;
          }
        }
      }
      // row-i reduction across the 16 column lanes (m15 bits)
#pragma unroll
      for (int off = 1; off <= 8; off <<= 1) {
        ull op = __shfl_xor(bp, off, 64);
        ull on = __shfl_xor(bn, off, 64);
        bp = bp > op ? bp : op;
        bn = bn < on ? bn : on;
      }
      if (m15 == 0) {
        if (bp != SENT_P) atomicMax(&best_pos[i], bp);
        if (bn != SENT_N) atomicMin(&best_neg[i], bn);
      }
    }
  }

  // col-j reduction across the 4 q lane-groups
#pragma unroll
  for (int ni = 0; ni < 4; ++ni) {
    ull cp = colBp[ni], cn = colBn[ni];
#pragma unroll
    for (int off = 16; off <= 32; off <<= 1) {
      ull op = __shfl_xor(cp, off, 64);
      ull on = __shfl_xor(cn, off, 64);
      cp = cp > op ? cp : op;
      cn = cn < on ? cn : on;
    }
    if (q == 0) {
      int j = jbase + wn * 64 + ni * 16 + m15;
      if (cp != SENT_P) atomicMax(&best_pos[j], cp);
      if (cn != SENT_N) atomicMin(&best_neg[j], cn);
    }
  }
}

// ---------------- loss + finalize in one single-block kernel ----------------
// valid anchor <=> bp != SENT_P && bn != SENT_N. dp/dn from the packed fp32
// dist plus the eps correction:
//   ||x+eps*1||^2 = ||x||^2 + 2 eps (sum_i - sum_j) + D eps^2
__global__ void k_loss_final(const ull* __restrict__ best_pos,
                             const ull* __restrict__ best_neg,
                             const float* __restrict__ rs,
                             float* __restrict__ out) {
  float per = 0.0f;
  int v = 0;
  for (int i = threadIdx.x; i < B; i += 1024) {
    ull bp = best_pos[i], bn = best_neg[i];
    if (bp != SENT_P && bn != SENT_N) {
      unsigned pRaw = ~(unsigned)bp;
      unsigned nRaw = (unsigned)bn;
      int pi = pRaw < (unsigned)B ? (int)pRaw : 0;
      int ni = nRaw < (unsigned)B ? (int)nRaw : 0;
      float distp = __uint_as_float((unsigned)(bp >> 32));
      float distn = __uint_as_float((unsigned)(bn >> 32));
      float ri = rs[i];
      const float e = 1e-6f, de2 = (float)D * 1e-12f;
      float dp2 = distp * distp + 2.0f * e * (ri - rs[pi]) + de2;
      float dn2 = distn * distn + 2.0f * e * (ri - rs[ni]) + de2;
      float dp = sqrtf(fmaxf(dp2, 0.0f));
      float dn = sqrtf(fmaxf(dn2, 0.0f));
      per += fmaxf(dp - dn + 0.3f, 0.0f);
      v += 1;
    }
  }
  for (int off = 32; off; off >>= 1) {
    per += __shfl_down(per, off, 64);
    v   += __shfl_down(v, off, 64);
  }
  __shared__ float pps[16];
  __shared__ int pvs[16];
  int lane = threadIdx.x & 63, wave = threadIdx.x >> 6;
  if (lane == 0) { pps[wave] = per; pvs[wave] = v; }
  __syncthreads();
  if (threadIdx.x == 0) {
    float t = 0.f;
    int cv = 0;
#pragma unroll
    for (int w = 0; w < 16; ++w) { t += pps[w]; cv += pvs[w]; }
    out[0] = cv > 0 ? t / (float)cv : 0.0f;
  }
}

// ---------------- launch -----------------------------------------------------
extern "C" void kernel_launch(void* const* d_in, const int* in_sizes, int n_in,
                              void* d_out, int out_size, void* d_ws, size_t ws_size,
                              hipStream_t stream) {
  const float* emb = (const float*)d_in[0];
  const int* labels = (const int*)d_in[1];
  float* out = (float*)d_out;
  char* ws = (char*)d_ws;

  const size_t off_embq = 0;
  const size_t off_sq   = off_embq + (size_t)B * D;       // 8 MiB
  const size_t off_rs   = off_sq + (size_t)B * 4;
  const size_t off_bp   = off_rs + (size_t)B * 4;
  const size_t off_bn   = off_bp + (size_t)B * 8;

  unsigned char* embq = (unsigned char*)(ws + off_embq);
  float* sq   = (float*)(ws + off_sq);
  float* rs   = (float*)(ws + off_rs);
  ull* bp     = (ull*)(ws + off_bp);
  ull* bn     = (ull*)(ws + off_bn);

  hipLaunchKernelGGL(k_convert_sq, dim3(B), dim3(256), 0, stream,
                     emb, embq, sq, rs, bp, bn);
  hipLaunchKernelGGL(k_gemm_select, dim3(1056), dim3(256), 0, stream,
                     embq, sq, labels, bp, bn);
  hipLaunchKernelGGL(k_loss_final, dim3(1), dim3(1024), 0, stream,
                     bp, bn, rs, out);
}

// Round 11
// 181.123 us; speedup vs baseline: 1.4049x; 1.1067x over previous
//
#include <hip/hip_runtime.h>
#include <stdint.h>

#define B 4096
#define D 2048
#define BK 128          // k-slab per barrier (fp8 elements; 128 B rows)
#define NTILES 1056

typedef unsigned long long ull;
typedef float f32x4 __attribute__((ext_vector_type(4)));

#define SENT_P 0x00000000FFFFFFFFull  // dist=0.0, ~idx -> "no positive seen"
#define SENT_N (~0ull)                // +inf      -> "no negative seen"

// ---------------- async global->LDS (16B per lane, wave-uniform LDS base) ----
__device__ __forceinline__ void async_copy16(const unsigned char* g, unsigned char* l) {
  __builtin_amdgcn_global_load_lds(
      (const __attribute__((address_space(1))) unsigned int*)g,
      (__attribute__((address_space(3))) unsigned int*)l,
      16, 0, 0);
}

// ---------------- fp32 -> fp8 e4m3 (OCP) + norms + sentinel init ------------
__global__ void k_convert_sq(const float* __restrict__ emb,
                             unsigned char* __restrict__ embq,
                             float* __restrict__ sq,
                             float* __restrict__ rs,
                             ull* __restrict__ bp,
                             ull* __restrict__ bn,
                             unsigned* __restrict__ done_ctr) {
  const int row = blockIdx.x, t = threadIdx.x;
  const float4* src = (const float4*)(emb + (size_t)row * D);
  float4 v0 = src[2 * t], v1 = src[2 * t + 1];
  float s = v0.x * v0.x + v0.y * v0.y + v0.z * v0.z + v0.w * v0.w
          + v1.x * v1.x + v1.y * v1.y + v1.z * v1.z + v1.w * v1.w;
  float sm = v0.x + v0.y + v0.z + v0.w + v1.x + v1.y + v1.z + v1.w;

  // pack 8 floats -> 8 fp8 bytes (v_cvt_pk_fp8_f32, OCP e4m3fn on gfx950)
  unsigned w0 = __builtin_amdgcn_cvt_pk_fp8_f32(v0.x, v0.y, 0, false);
  w0 = __builtin_amdgcn_cvt_pk_fp8_f32(v0.z, v0.w, w0, true);
  unsigned w1 = __builtin_amdgcn_cvt_pk_fp8_f32(v1.x, v1.y, 0, false);
  w1 = __builtin_amdgcn_cvt_pk_fp8_f32(v1.z, v1.w, w1, true);
  uint2 o; o.x = w0; o.y = w1;
  ((uint2*)(embq + (size_t)row * D))[t] = o;

  for (int off = 32; off; off >>= 1) {
    s  += __shfl_down(s, off, 64);
    sm += __shfl_down(sm, off, 64);
  }
  __shared__ float ps[4], pm[4];
  int lane = t & 63, wave = t >> 6;
  if (lane == 0) { ps[wave] = s; pm[wave] = sm; }
  __syncthreads();
  if (t == 0) {
    sq[row] = ps[0] + ps[1] + ps[2] + ps[3];
    rs[row] = pm[0] + pm[1] + pm[2] + pm[3];
    bp[row] = SENT_P;
    bn[row] = SENT_N;
    if (row == 0) *done_ctr = 0;
  }
}

// ---------------- fused symmetric fp8 GEMM + selection + tail loss ----------
// R8's proven engine (55.7 us): 64x128 tiles over the strict upper triangle
// (j > i), sequential triangular decode, BK=128 fp8 = 128 B rows -> 16
// k-iterations, 32 mfma_f32_16x16x32_fp8_fp8 per wave per barrier pair.
// Rows are 8 chunks of 16 B; chunk c at slot c ^ (row&7) keeps
// global_load_lds's wave-uniform-base layout. (Known cost: b64 fragment
// reads hit even-bank 4-way conflicts, ~6.5M cycles — accepted; the MX
// b128 engine that would fix it spills at any reachable VGPR budget,
// R9/R10.) NEW vs R8: the final loss is fused as a done-counter tail —
// the last of 1056 blocks reduces the loss (identity device-scope atomics
// give cross-XCD-coherent reads), saving one ~14 us launch node + the
// loss kernel's dispatch.
__launch_bounds__(256, 4)
__global__ void k_gemm_select(const unsigned char* __restrict__ embq,
                              const float* __restrict__ sq,
                              const int* __restrict__ labels,
                              ull* __restrict__ best_pos,
                              ull* __restrict__ best_neg,
                              const float* __restrict__ rs,
                              unsigned* __restrict__ done_ctr,
                              float* __restrict__ out) {
  __shared__ unsigned char ldsA[64 * BK];    // 8 KB
  __shared__ unsigned char ldsB[128 * BK];   // 16 KB

  // linear bid -> (by in [0,64), bx in [0,32)) with bx*128+127 > by*64
  int rem = blockIdx.x, p = 0;
  while (rem >= 2 * (32 - p)) { rem -= 2 * (32 - p); ++p; }
  int by = 2 * p;
  int c = 32 - p;
  if (rem >= c) { by += 1; rem -= c; }
  const int bx = p + rem;

  const int tid  = threadIdx.x;
  const int lane = tid & 63;
  const int wave = tid >> 6;
  const int wm = wave >> 1, wn = wave & 1;
  const int q = lane >> 4, m15 = lane & 15;
  const int ibase = by * 64, jbase = bx * 128;

  // fragment read offsets (bytes) for slab s (k=s*32..s*32+31), row-group xg:
  //   row = base + xg*16 + m15 ; chunk = s*2 + (q>>1) ; slot = chunk ^ (row&7)
  //   byte = row*128 + slot*16 + (q&1)*8
  int aoff[4][2], boff[4][4];
#pragma unroll
  for (int s = 0; s < 4; ++s) {
#pragma unroll
    for (int xg = 0; xg < 2; ++xg) {
      int row = wm * 32 + xg * 16 + m15;
      aoff[s][xg] = row * BK + (((s * 2 + (q >> 1)) ^ (row & 7)) * 16) + (q & 1) * 8;
    }
#pragma unroll
    for (int xg = 0; xg < 4; ++xg) {
      int row = wn * 64 + xg * 16 + m15;
      boff[s][xg] = row * BK + (((s * 2 + (q >> 1)) ^ (row & 7)) * 16) + (q & 1) * 8;
    }
  }

  const int srow = lane >> 3;  // row within 8-row staging group
  const int slot = lane & 7;   // 16B slot within 128B row

  f32x4 acc[2][4];
  const f32x4 z = {0.f, 0.f, 0.f, 0.f};
#pragma unroll
  for (int a = 0; a < 2; ++a)
#pragma unroll
    for (int b = 0; b < 4; ++b) acc[a][b] = z;

  for (int kb = 0; kb < D; kb += BK) {
    __syncthreads();
#pragma unroll
    for (int pp = 0; pp < 2; ++pp) {
      // A: 64 rows -> 8 issues (8 rows each), two per wave
      int r0  = wave * 16 + pp * 8;  // wave-uniform
      int row = r0 + srow;
      int g   = (slot ^ (row & 7)) * 16;
      const unsigned char* ga = embq + (size_t)(ibase + row) * D + kb + g;
      async_copy16(ga, &ldsA[r0 * BK]);
    }
#pragma unroll
    for (int pp = 0; pp < 4; ++pp) {
      // B: 128 rows -> 16 issues, four per wave
      int r0  = wave * 32 + pp * 8;  // wave-uniform
      int row = r0 + srow;
      int g   = (slot ^ (row & 7)) * 16;
      const unsigned char* gb = embq + (size_t)(jbase + row) * D + kb + g;
      async_copy16(gb, &ldsB[r0 * BK]);
    }
    __syncthreads();

#pragma unroll
    for (int s = 0; s < 4; ++s) {
      long af[2];
      long bfr[4];
#pragma unroll
      for (int xg = 0; xg < 2; ++xg) af[xg] = *(const long*)&ldsA[aoff[s][xg]];
#pragma unroll
      for (int xg = 0; xg < 4; ++xg) bfr[xg] = *(const long*)&ldsB[boff[s][xg]];
#pragma unroll
      for (int mi = 0; mi < 2; ++mi)
#pragma unroll
        for (int ni = 0; ni < 4; ++ni)
          acc[mi][ni] = __builtin_amdgcn_mfma_f32_16x16x32_fp8_fp8(
              af[mi], bfr[ni], acc[mi][ni], 0, 0, 0);
    }
  }

  // ---- epilogue (C/D layout: col=lane&15, row=q*4+r) ----
  float sqj[4];
  int labj[4];
#pragma unroll
  for (int ni = 0; ni < 4; ++ni) {
    int jj = jbase + wn * 64 + ni * 16 + m15;
    sqj[ni] = sq[jj];
    labj[ni] = labels[jj];
  }

  ull colBp[4], colBn[4];
#pragma unroll
  for (int ni = 0; ni < 4; ++ni) { colBp[ni] = SENT_P; colBn[ni] = SENT_N; }

#pragma unroll
  for (int mi = 0; mi < 2; ++mi) {
#pragma unroll
    for (int r = 0; r < 4; ++r) {
      const int i = ibase + wm * 32 + mi * 16 + q * 4 + r;
      const float si = sq[i];
      const int li = labels[i];
      ull bp = SENT_P;
      ull bn = SENT_N;
#pragma unroll
      for (int ni = 0; ni < 4; ++ni) {
        int jj = jbase + wn * 64 + ni * 16 + m15;
        if (jj > i) {  // strict upper triangle only
          float dot = acc[mi][ni][r];
          float d2 = si + sqj[ni] - 2.0f * dot;
          float dist = sqrtf(fmaxf(d2, 0.0f));
          ull pv = ((ull)__float_as_uint(dist)) << 32;
          if (labj[ni] == li) {
            ull cr = pv | (unsigned)(~jj);  // max -> smallest idx wins ties
            bp = bp > cr ? bp : cr;
            ull cc = pv | (unsigned)(~i);
            colBp[ni] = colBp[ni] > cc ? colBp[ni] : cc;
          } else {
            ull cr = pv | (unsigned)jj;     // min -> smallest idx wins ties
            bn = bn < cr ? bn : cr;
            ull cc = pv | (unsigned)i;
            colBn[ni] = colBn[ni] < cc ? colBn[ni] : cc;
          }
        }
      }
      // row-i reduction across the 16 column lanes (m15 bits)
#pragma unroll
      for (int off = 1; off <= 8; off <<= 1) {
        ull op = __shfl_xor(bp, off, 64);
        ull on = __shfl_xor(bn, off, 64);
        bp = bp > op ? bp : op;
        bn = bn < on ? bn : on;
      }
      if (m15 == 0) {
        if (bp != SENT_P) atomicMax(&best_pos[i], bp);
        if (bn != SENT_N) atomicMin(&best_neg[i], bn);
      }
    }
  }

  // col-j reduction across the 4 q lane-groups
#pragma unroll
  for (int ni = 0; ni < 4; ++ni) {
    ull cp = colBp[ni], cn = colBn[ni];
#pragma unroll
    for (int off = 16; off <= 32; off <<= 1) {
      ull op = __shfl_xor(cp, off, 64);
      ull on = __shfl_xor(cn, off, 64);
      cp = cp > op ? cp : op;
      cn = cn < on ? cn : on;
    }
    if (q == 0) {
      int j = jbase + wn * 64 + ni * 16 + m15;
      if (cp != SENT_P) atomicMax(&best_pos[j], cp);
      if (cn != SENT_N) atomicMin(&best_neg[j], cn);
    }
  }

  // ---- tail: last block computes the final loss ----
  __threadfence();
  __shared__ unsigned done;
  if (tid == 0) done = atomicAdd(done_ctr, 1u);
  __syncthreads();
  if (done == NTILES - 1) {
    float per = 0.0f;
    int v = 0;
    for (int i = tid; i < B; i += 256) {
      // identity atomics -> device-scope-coherent reads of other XCDs' results
      ull bp = atomicMax(&best_pos[i], 0ull);
      ull bn = atomicAdd(&best_neg[i], 0ull);
      if (bp != SENT_P && bn != SENT_N) {
        unsigned pRaw = ~(unsigned)bp;
        unsigned nRaw = (unsigned)bn;
        int pi = pRaw < (unsigned)B ? (int)pRaw : 0;
        int nj = nRaw < (unsigned)B ? (int)nRaw : 0;
        float distp = __uint_as_float((unsigned)(bp >> 32));
        float distn = __uint_as_float((unsigned)(bn >> 32));
        float ri = rs[i];
        // ||x+eps*1||^2 = ||x||^2 + 2 eps (sum_i - sum_j) + D eps^2
        const float e = 1e-6f, de2 = (float)D * 1e-12f;
        float dp2 = distp * distp + 2.0f * e * (ri - rs[pi]) + de2;
        float dn2 = distn * distn + 2.0f * e * (ri - rs[nj]) + de2;
        float dp = sqrtf(fmaxf(dp2, 0.0f));
        float dn = sqrtf(fmaxf(dn2, 0.0f));
        per += fmaxf(dp - dn + 0.3f, 0.0f);
        v += 1;
      }
    }
    for (int off = 32; off; off >>= 1) {
      per += __shfl_down(per, off, 64);
      v   += __shfl_down(v, off, 64);
    }
    __shared__ float pps[4];
    __shared__ int pvs[4];
    if (lane == 0) { pps[wave] = per; pvs[wave] = v; }
    __syncthreads();
    if (tid == 0) {
      float t = pps[0] + pps[1] + pps[2] + pps[3];
      int cv = pvs[0] + pvs[1] + pvs[2] + pvs[3];
      out[0] = cv > 0 ? t / (float)cv : 0.0f;
    }
  }
}

// ---------------- launch -----------------------------------------------------
extern "C" void kernel_launch(void* const* d_in, const int* in_sizes, int n_in,
                              void* d_out, int out_size, void* d_ws, size_t ws_size,
                              hipStream_t stream) {
  const float* emb = (const float*)d_in[0];
  const int* labels = (const int*)d_in[1];
  float* out = (float*)d_out;
  char* ws = (char*)d_ws;

  const size_t off_embq = 0;
  const size_t off_sq   = off_embq + (size_t)B * D;       // 8 MiB
  const size_t off_rs   = off_sq + (size_t)B * 4;
  const size_t off_bp   = off_rs + (size_t)B * 4;
  const size_t off_bn   = off_bp + (size_t)B * 8;
  const size_t off_ctr  = off_bn + (size_t)B * 8;

  unsigned char* embq = (unsigned char*)(ws + off_embq);
  float* sq   = (float*)(ws + off_sq);
  float* rs   = (float*)(ws + off_rs);
  ull* bp     = (ull*)(ws + off_bp);
  ull* bn     = (ull*)(ws + off_bn);
  unsigned* ctr = (unsigned*)(ws + off_ctr);

  hipLaunchKernelGGL(k_convert_sq, dim3(B), dim3(256), 0, stream,
                     emb, embq, sq, rs, bp, bn, ctr);
  hipLaunchKernelGGL(k_gemm_select, dim3(NTILES), dim3(256), 0, stream,
                     embq, sq, labels, bp, bn, rs, ctr, out);
}

// Round 12
// 131.624 us; speedup vs baseline: 1.9332x; 1.3761x over previous
//
#include <hip/hip_runtime.h>
#include <stdint.h>

#define B 4096
#define D 2048
#define BK 128          // k-slab per barrier (fp8 elements; 128 B rows)

typedef unsigned long long ull;
typedef float f32x4 __attribute__((ext_vector_type(4)));

#define SENT_P 0x00000000FFFFFFFFull  // dist=0.0, ~idx -> "no positive seen"
#define SENT_N (~0ull)                // +inf      -> "no negative seen"

// ---------------- async global->LDS (16B per lane, wave-uniform LDS base) ----
__device__ __forceinline__ void async_copy16(const unsigned char* g, unsigned char* l) {
  __builtin_amdgcn_global_load_lds(
      (const __attribute__((address_space(1))) unsigned int*)g,
      (__attribute__((address_space(3))) unsigned int*)l,
      16, 0, 0);
}

// ---------------- fp32 -> fp8 e4m3 (OCP) + norms + sentinel init ------------
__global__ void k_convert_sq(const float* __restrict__ emb,
                             unsigned char* __restrict__ embq,
                             float* __restrict__ sq,
                             float* __restrict__ rs,
                             ull* __restrict__ bp,
                             ull* __restrict__ bn) {
  const int row = blockIdx.x, t = threadIdx.x;
  const float4* src = (const float4*)(emb + (size_t)row * D);
  float4 v0 = src[2 * t], v1 = src[2 * t + 1];
  float s = v0.x * v0.x + v0.y * v0.y + v0.z * v0.z + v0.w * v0.w
          + v1.x * v1.x + v1.y * v1.y + v1.z * v1.z + v1.w * v1.w;
  float sm = v0.x + v0.y + v0.z + v0.w + v1.x + v1.y + v1.z + v1.w;

  unsigned w0 = __builtin_amdgcn_cvt_pk_fp8_f32(v0.x, v0.y, 0, false);
  w0 = __builtin_amdgcn_cvt_pk_fp8_f32(v0.z, v0.w, w0, true);
  unsigned w1 = __builtin_amdgcn_cvt_pk_fp8_f32(v1.x, v1.y, 0, false);
  w1 = __builtin_amdgcn_cvt_pk_fp8_f32(v1.z, v1.w, w1, true);
  uint2 o; o.x = w0; o.y = w1;
  ((uint2*)(embq + (size_t)row * D))[t] = o;

  for (int off = 32; off; off >>= 1) {
    s  += __shfl_down(s, off, 64);
    sm += __shfl_down(sm, off, 64);
  }
  __shared__ float ps[4], pm[4];
  int lane = t & 63, wave = t >> 6;
  if (lane == 0) { ps[wave] = s; pm[wave] = sm; }
  __syncthreads();
  if (t == 0) {
    sq[row] = ps[0] + ps[1] + ps[2] + ps[3];
    rs[row] = pm[0] + pm[1] + pm[2] + pm[3];
    bp[row] = SENT_P;
    bn[row] = SENT_N;
  }
}

// ---------------- fused symmetric fp8 GEMM + hard pos/neg selection ---------
// 64x128 tiles over the strict upper triangle (j > i): 1056 blocks,
// sequential triangular decode. NEW vs R8: 2 waves (128 thr) instead of 4;
// each wave owns a 64x64 region (full A rows x its col half) -> per-iter
// LDS fragment reads drop 48KB -> 32KB at identical MACs/staged bytes, and
// MFMA per wave per barrier doubles to 64. acc = 4x4 f32x4 (64 VGPRs);
// __launch_bounds__(128,3) caps ~170 VGPR so nothing spills (R9/R10
// lesson). LDS 24KB -> 6 blocks/CU = 12 waves/CU. Staging layout and
// XOR chunk swizzle (slot = chunk ^ (row&7)) identical to R8; known b64
// even-bank conflict cost accepted. No fences anywhere (R11 lesson).
__launch_bounds__(128, 3)
__global__ void k_gemm_select(const unsigned char* __restrict__ embq,
                              const float* __restrict__ sq,
                              const int* __restrict__ labels,
                              ull* __restrict__ best_pos,
                              ull* __restrict__ best_neg) {
  __shared__ unsigned char ldsA[64 * BK];    // 8 KB
  __shared__ unsigned char ldsB[128 * BK];   // 16 KB

  // linear bid -> (by in [0,64), bx in [0,32)) with bx*128+127 > by*64
  int rem = blockIdx.x, p = 0;
  while (rem >= 2 * (32 - p)) { rem -= 2 * (32 - p); ++p; }
  int by = 2 * p;
  int c = 32 - p;
  if (rem >= c) { by += 1; rem -= c; }
  const int bx = p + rem;

  const int tid  = threadIdx.x;
  const int lane = tid & 63;
  const int wave = tid >> 6;          // 0/1 = column half
  const int wn = wave;
  const int q = lane >> 4, m15 = lane & 15;
  const int ibase = by * 64, jbase = bx * 128;

  // fragment read offsets (bytes) for slab s (k=s*32..+31), row-group xg:
  //   row = base + xg*16 + m15 ; chunk = s*2 + (q>>1) ; slot = chunk ^ (row&7)
  //   byte = row*128 + slot*16 + (q&1)*8
  int aoff[4][4], boff[4][4];
#pragma unroll
  for (int s = 0; s < 4; ++s) {
#pragma unroll
    for (int xg = 0; xg < 4; ++xg) {
      int rowA = xg * 16 + m15;                 // full 64 A rows per wave
      aoff[s][xg] = rowA * BK + (((s * 2 + (q >> 1)) ^ (rowA & 7)) * 16) + (q & 1) * 8;
      int rowB = wn * 64 + xg * 16 + m15;       // wave's 64-col B half
      boff[s][xg] = rowB * BK + (((s * 2 + (q >> 1)) ^ (rowB & 7)) * 16) + (q & 1) * 8;
    }
  }

  const int srow = lane >> 3;  // row within 8-row staging group
  const int slot = lane & 7;   // 16B slot within 128B row

  f32x4 acc[4][4];
  const f32x4 z = {0.f, 0.f, 0.f, 0.f};
#pragma unroll
  for (int a = 0; a < 4; ++a)
#pragma unroll
    for (int b = 0; b < 4; ++b) acc[a][b] = z;

  for (int kb = 0; kb < D; kb += BK) {
    __syncthreads();
#pragma unroll
    for (int pp = 0; pp < 4; ++pp) {
      // A: 64 rows -> 8 issues (8 rows each), four per wave
      int r0  = wave * 32 + pp * 8;  // wave-uniform
      int row = r0 + srow;
      int g   = (slot ^ (row & 7)) * 16;
      const unsigned char* ga = embq + (size_t)(ibase + row) * D + kb + g;
      async_copy16(ga, &ldsA[r0 * BK]);
    }
#pragma unroll
    for (int pp = 0; pp < 8; ++pp) {
      // B: 128 rows -> 16 issues, eight per wave
      int r0  = wave * 64 + pp * 8;  // wave-uniform
      int row = r0 + srow;
      int g   = (slot ^ (row & 7)) * 16;
      const unsigned char* gb = embq + (size_t)(jbase + row) * D + kb + g;
      async_copy16(gb, &ldsB[r0 * BK]);
    }
    __syncthreads();

#pragma unroll
    for (int s = 0; s < 4; ++s) {
      long af[4];
      long bfr[4];
#pragma unroll
      for (int xg = 0; xg < 4; ++xg) af[xg] = *(const long*)&ldsA[aoff[s][xg]];
#pragma unroll
      for (int xg = 0; xg < 4; ++xg) bfr[xg] = *(const long*)&ldsB[boff[s][xg]];
#pragma unroll
      for (int mi = 0; mi < 4; ++mi)
#pragma unroll
        for (int ni = 0; ni < 4; ++ni)
          acc[mi][ni] = __builtin_amdgcn_mfma_f32_16x16x32_fp8_fp8(
              af[mi], bfr[ni], acc[mi][ni], 0, 0, 0);
    }
  }

  // ---- epilogue (C/D layout: col=lane&15, row=q*4+r) ----
  float sqj[4];
  int labj[4];
#pragma unroll
  for (int ni = 0; ni < 4; ++ni) {
    int jj = jbase + wn * 64 + ni * 16 + m15;
    sqj[ni] = sq[jj];
    labj[ni] = labels[jj];
  }

  ull colBp[4], colBn[4];
#pragma unroll
  for (int ni = 0; ni < 4; ++ni) { colBp[ni] = SENT_P; colBn[ni] = SENT_N; }

#pragma unroll
  for (int mi = 0; mi < 4; ++mi) {
#pragma unroll
    for (int r = 0; r < 4; ++r) {
      const int i = ibase + mi * 16 + q * 4 + r;
      const float si = sq[i];
      const int li = labels[i];
      ull bp = SENT_P;
      ull bn = SENT_N;
#pragma unroll
      for (int ni = 0; ni < 4; ++ni) {
        int jj = jbase + wn * 64 + ni * 16 + m15;
        if (jj > i) {  // strict upper triangle only
          float dot = acc[mi][ni][r];
          float d2 = si + sqj[ni] - 2.0f * dot;
          float dist = sqrtf(fmaxf(d2, 0.0f));
          ull pv = ((ull)__float_as_uint(dist)) << 32;
          if (labj[ni] == li) {
            ull cr = pv | (unsigned)(~jj);  // max -> smallest idx wins ties
            bp = bp > cr ? bp : cr;
            ull cc = pv | (unsigned)(~i);
            colBp[ni] = colBp[ni] > cc ? colBp[ni] : cc;
          } else {
            ull cr = pv | (unsigned)jj;     // min -> smallest idx wins ties
            bn = bn < cr ? bn : cr;
            ull cc = pv | (unsigned)i;
            colBn[ni] = colBn[ni] < cc ? colBn[ni] : cc;
          }
        }
      }
      // row-i reduction across the 16 column lanes (m15 bits); both waves
      // update the same rows via atomics (different col halves) -> merges.
#pragma unroll
      for (int off = 1; off <= 8; off <<= 1) {
        ull op = __shfl_xor(bp, off, 64);
        ull on = __shfl_xor(bn, off, 64);
        bp = bp > op ? bp : op;
        bn = bn < on ? bn : on;
      }
      if (m15 == 0) {
        if (bp != SENT_P) atomicMax(&best_pos[i], bp);
        if (bn != SENT_N) atomicMin(&best_neg[i], bn);
      }
    }
  }

  // col-j reduction across the 4 q lane-groups
#pragma unroll
  for (int ni = 0; ni < 4; ++ni) {
    ull cp = colBp[ni], cn = colBn[ni];
#pragma unroll
    for (int off = 16; off <= 32; off <<= 1) {
      ull op = __shfl_xor(cp, off, 64);
      ull on = __shfl_xor(cn, off, 64);
      cp = cp > op ? cp : op;
      cn = cn < on ? cn : on;
    }
    if (q == 0) {
      int j = jbase + wn * 64 + ni * 16 + m15;
      if (cp != SENT_P) atomicMax(&best_pos[j], cp);
      if (cn != SENT_N) atomicMin(&best_neg[j], cn);
    }
  }
}

// ---------------- loss + finalize in one single-block kernel ----------------
// valid anchor <=> bp != SENT_P && bn != SENT_N. dp/dn from the packed fp32
// dist plus the eps correction:
//   ||x+eps*1||^2 = ||x||^2 + 2 eps (sum_i - sum_j) + D eps^2
__global__ void k_loss_final(const ull* __restrict__ best_pos,
                             const ull* __restrict__ best_neg,
                             const float* __restrict__ rs,
                             float* __restrict__ out) {
  float per = 0.0f;
  int v = 0;
  for (int i = threadIdx.x; i < B; i += 1024) {
    ull bp = best_pos[i], bn = best_neg[i];
    if (bp != SENT_P && bn != SENT_N) {
      unsigned pRaw = ~(unsigned)bp;
      unsigned nRaw = (unsigned)bn;
      int pi = pRaw < (unsigned)B ? (int)pRaw : 0;
      int ni = nRaw < (unsigned)B ? (int)nRaw : 0;
      float distp = __uint_as_float((unsigned)(bp >> 32));
      float distn = __uint_as_float((unsigned)(bn >> 32));
      float ri = rs[i];
      const float e = 1e-6f, de2 = (float)D * 1e-12f;
      float dp2 = distp * distp + 2.0f * e * (ri - rs[pi]) + de2;
      float dn2 = distn * distn + 2.0f * e * (ri - rs[ni]) + de2;
      float dp = sqrtf(fmaxf(dp2, 0.0f));
      float dn = sqrtf(fmaxf(dn2, 0.0f));
      per += fmaxf(dp - dn + 0.3f, 0.0f);
      v += 1;
    }
  }
  for (int off = 32; off; off >>= 1) {
    per += __shfl_down(per, off, 64);
    v   += __shfl_down(v, off, 64);
  }
  __shared__ float pps[16];
  __shared__ int pvs[16];
  int lane = threadIdx.x & 63, wave = threadIdx.x >> 6;
  if (lane == 0) { pps[wave] = per; pvs[wave] = v; }
  __syncthreads();
  if (threadIdx.x == 0) {
    float t = 0.f;
    int cv = 0;
#pragma unroll
    for (int w = 0; w < 16; ++w) { t += pps[w]; cv += pvs[w]; }
    out[0] = cv > 0 ? t / (float)cv : 0.0f;
  }
}

// ---------------- launch -----------------------------------------------------
extern "C" void kernel_launch(void* const* d_in, const int* in_sizes, int n_in,
                              void* d_out, int out_size, void* d_ws, size_t ws_size,
                              hipStream_t stream) {
  const float* emb = (const float*)d_in[0];
  const int* labels = (const int*)d_in[1];
  float* out = (float*)d_out;
  char* ws = (char*)d_ws;

  const size_t off_embq = 0;
  const size_t off_sq   = off_embq + (size_t)B * D;       // 8 MiB
  const size_t off_rs   = off_sq + (size_t)B * 4;
  const size_t off_bp   = off_rs + (size_t)B * 4;
  const size_t off_bn   = off_bp + (size_t)B * 8;

  unsigned char* embq = (unsigned char*)(ws + off_embq);
  float* sq   = (float*)(ws + off_sq);
  float* rs   = (float*)(ws + off_rs);
  ull* bp     = (ull*)(ws + off_bp);
  ull* bn     = (ull*)(ws + off_bn);

  hipLaunchKernelGGL(k_convert_sq, dim3(B), dim3(256), 0, stream,
                     emb, embq, sq, rs, bp, bn);
  hipLaunchKernelGGL(k_gemm_select, dim3(1056), dim3(128), 0, stream,
                     embq, sq, labels, bp, bn);
  hipLaunchKernelGGL(k_loss_final, dim3(1), dim3(1024), 0, stream,
                     bp, bn, rs, out);
}